// Round 10
// baseline (2398.758 us; speedup 1.0000x reference)
//
#include <hip/hip_runtime.h>
#include <hip/hip_bf16.h>
#include <math.h>

// Problem dims (fixed by the reference)
#define T_  512
#define B_  64
#define I_  512
#define H_  1024
#define HX_ 1536
#define NG  4096          // 4*H packed gate rows
#define RP  17            // fallback reduce-buffer pitch (fp32)
#define RP3 65            // v10 reduce-buffer pitch: [kq][32 rows][64 cols]
#define NBLK 128          // v10 grid: 128 blocks (1 block/CU on half the CUs)

// Barrier: flag[mh*64 + nt] is ONE dword. Group = 64 flags = 256B = 2 lines.
#define BAR_INTS  1024    // 4KB buffer (only 128 used)

typedef __attribute__((ext_vector_type(8))) short bf16x8;
typedef __attribute__((ext_vector_type(4))) float floatx4;
typedef unsigned long long ull;

__device__ __forceinline__ float sigmoidf_(float v) { return 1.0f / (1.0f + __expf(-v)); }
__device__ __forceinline__ float tanhf_(float v) {
    float e = __expf(-2.0f * fabsf(v));
    float t = (1.0f - e) / (1.0f + e);
    return copysignf(t, v);
}
__device__ __forceinline__ short f2bf(float f) {
    union { __hip_bfloat16 b; short s; } u;
    u.b = __float2bfloat16(f);   // RNE
    return u.s;
}
__device__ __forceinline__ ull pack4bf(float a, float b, float c, float d) {
    return (ull)(unsigned short)f2bf(a)
         | ((ull)(unsigned short)f2bf(b) << 16)
         | ((ull)(unsigned short)f2bf(c) << 32)
         | ((ull)(unsigned short)f2bf(d) << 48);
}

// ---- prologue: pack Wg -> Wp [4096][HX] bf16, rows r = u*4+g; biases too ----
__global__ __launch_bounds__(256) void pack_w(
    const float* __restrict__ Wf, const float* __restrict__ Wi,
    const float* __restrict__ Wc, const float* __restrict__ Wo,
    const float* __restrict__ bf, const float* __restrict__ bi,
    const float* __restrict__ bc, const float* __restrict__ bo,
    short* __restrict__ Wp, float* __restrict__ bp)
{
    const int r = blockIdx.x;          // 0..4095
    const int u = r >> 2, g = r & 3;
    const float* src; const float* bsrc;
    switch (g) {
        case 0:  src = Wf; bsrc = bf; break;
        case 1:  src = Wi; bsrc = bi; break;
        case 2:  src = Wc; bsrc = bc; break;
        default: src = Wo; bsrc = bo; break;
    }
    src += (size_t)u * HX_;
    for (int off = threadIdx.x; off < HX_; off += 256)
        Wp[(size_t)r * HX_ + off] = f2bf(src[off]);
    if (threadIdx.x == 0) bp[r] = bsrc[u];
}

// ---- persistent-path init: stage bf16(x_t) into hxall[t] x-part for ALL t,
//      zero hxall[0] h-part, zero barrier flags ----
__global__ __launch_bounds__(256) void init_hxall(
    const float* __restrict__ x, short* __restrict__ hxall, unsigned* __restrict__ bar)
{
    const int idx = blockIdx.x * 256 + threadIdx.x;
    const int nx4 = T_ * B_ * I_ / 4;               // 4,194,304 quads
    if (idx < nx4) {
        const int e = idx * 4;                      // element index into x
        const int t = e >> 15;                      // / (B_*I_)
        const int r = e & (B_ * I_ - 1);
        const int b = r >> 9, p = r & 511;
        const float4 xv = *(const float4*)(x + (size_t)e);
        *(ull*)(hxall + (size_t)t * (B_ * HX_) + (size_t)b * HX_ + H_ + p)
            = pack4bf(xv.x, xv.y, xv.z, xv.w);
    } else if (idx < nx4 + B_ * H_ / 4) {           // zero slot-0 h-part
        const int k = (idx - nx4) * 4;
        const int b = k >> 10, p = k & 1023;
        *(ull*)(hxall + (size_t)b * HX_ + p) = 0ull;
    }
    if (idx < BAR_INTS) bar[idx] = 0u;
}

// ---- persistent LSTM v10: 128 blocks x 512 thr ----
// Derived from the verified v9 (2174 us). Change: each block covers N=64
// gate-cols (FOUR 16-col tiles sharing ONE set of A-fragments per wave) ->
// grid and barrier participants halve again (2 groups x 64), total L2
// A-traffic halves (12 MB/step), straggler population halves. The barrier
// poll collapses to ONE flag per lane (64 lanes cover the group in a single
// 256B round). Weight fragments (48/wave) ride in AGPRs (v9 evidence:
// VGPR_Count 80 with 24 frags). Barrier pattern, K-split, x-phase overlap,
// post-flag out store identical to v9. Epilogue uses all 512 threads
// (32 rows x 16 units).
__global__ __launch_bounds__(512, 2) void lstm_all(
    const short* __restrict__ Wp, const float* __restrict__ bp,
    short* __restrict__ hxall,            // [T_+1][B_][HX_] bf16
    unsigned* __restrict__ bar,
    float* __restrict__ out)              // [T_][B_][H_]
{
    __shared__ __align__(16) float red[4 * 32 * RP3];   // 33,280 B

    const int tid  = threadIdx.x;
    const int bid  = blockIdx.x;          // 0..127
    const int nt   = bid & 63;            // 64-gate-col group
    const int mh   = bid >> 6;            // batch half
    const int lane = tid & 63;
    const int wv   = tid >> 6;            // 0..7
    const int w    = wv & 1;              // M 16-row half
    const int kq   = wv >> 1;             // K quarter
    const int n16  = lane & 15;
    const int quad = lane >> 4;
    const int n0   = nt * 64;             // packed gate-col base (64 cols)
    const int j0   = nt * 16;             // hidden-unit base (16 units)
    const int mrow = mh * 32 + w * 16 + n16;

    // Weights: pinned for all 512 steps. Four N-tiles: 4x(8 h + 4 x) frags.
    bf16x8 bfh[4][8], bfx[4][4];
    {
        const short* brow = Wp + (size_t)(n0 + n16) * HX_ + quad * 8;
        #pragma unroll
        for (int s = 0; s < 4; ++s) {
            const short* br = brow + (size_t)(s * 16) * HX_;
            #pragma unroll
            for (int f = 0; f < 8; ++f) bfh[s][f] = *(const bf16x8*)(br + kq * 256 + f * 32);
            #pragma unroll
            for (int f = 0; f < 4; ++f) bfx[s][f] = *(const bf16x8*)(br + 1024 + kq * 128 + f * 32);
        }
    }

    // Epilogue-role constants (all 512 threads): thread = (row b_loc, unit j0+uu)
    const int b_loc = tid >> 4;           // 0..31
    const int uu    = tid & 15;           // 0..15
    const int gb    = mh * 32 + b_loc;
    const float4 bias = *(const float4*)(bp + n0 + uu * 4);
    float c = 0.0f;

    // Running pointers (advance one time-slot per step)
    const short* sp = hxall + (size_t)mrow * HX_ + quad * 8;                 // A row base, slot t
    ull* hd = (ull*)(hxall + (size_t)(B_ * HX_) + (size_t)gb * HX_ + j0 + (uu & 12)); // h dst slot t+1
    float* op = out + (size_t)gb * H_ + j0 + uu;

    unsigned* const flagp = bar + (unsigned)(mh * 64 + nt);                  // own dword
    const unsigned* const pollp = bar + (unsigned)(mh * 64 + lane);          // 1 flag/lane

    // x-phase for t=0 (x-part of A is init-staged for all t)
    floatx4 acc[4];
    #pragma unroll
    for (int s = 0; s < 4; ++s) acc[s] = floatx4{0.f, 0.f, 0.f, 0.f};
    {
        const short* ax = sp + 1024 + kq * 128;
        bf16x8 xa[4];
        #pragma unroll
        for (int f = 0; f < 4; ++f) xa[f] = *(const bf16x8*)(ax + f * 32);
        #pragma unroll
        for (int f = 0; f < 4; ++f) {
            #pragma unroll
            for (int s = 0; s < 4; ++s)
                acc[s] = __builtin_amdgcn_mfma_f32_16x16x32_bf16(xa[f], bfx[s][f], acc[s], 0, 0, 0);
        }
    }

    for (int t = 0; t < T_; ++t) {
        // h-phase: 8 shared A-frag loads feed FOUR N-tiles (32 MFMAs)
        {
            const short* ah = sp + kq * 256;
            bf16x8 ha[8];
            #pragma unroll
            for (int i = 0; i < 8; ++i) ha[i] = *(const bf16x8*)(ah + i * 32);
            #pragma unroll
            for (int kf = 0; kf < 8; ++kf) {
                #pragma unroll
                for (int s = 0; s < 4; ++s)
                    acc[s] = __builtin_amdgcn_mfma_f32_16x16x32_bf16(ha[kf], bfh[s][kf], acc[s], 0, 0, 0);
            }
        }

        // C/D layout: batch row = quad*4 + reg (within w-half), gate col = s*16 + n16
        #pragma unroll
        for (int i2 = 0; i2 < 4; ++i2) {
            const int rr = (kq * 32 + w * 16 + quad * 4 + i2) * RP3 + n16;
            red[rr]      = acc[0][i2];
            red[rr + 16] = acc[1][i2];
            red[rr + 32] = acc[2][i2];
            red[rr + 48] = acc[3][i2];
        }
        __syncthreads();

        float h;
        {
            float gv[4];
            #pragma unroll
            for (int gg = 0; gg < 4; ++gg) {
                const int col = uu * 4 + gg;
                gv[gg] = red[(0 * 32 + b_loc) * RP3 + col]
                       + red[(1 * 32 + b_loc) * RP3 + col]
                       + red[(2 * 32 + b_loc) * RP3 + col]
                       + red[(3 * 32 + b_loc) * RP3 + col];
            }
            const float F  = sigmoidf_(gv[0] + bias.x);
            const float In = sigmoidf_(gv[1] + bias.y);
            const float G  = tanhf_(gv[2] + bias.z);
            const float O  = sigmoidf_(gv[3] + bias.w);
            c = F * c + In * G;
            h = O * tanhf_(c);
            // pack 4 adjacent units (same b_loc) into one 8B agent store
            const int hv = (int)(unsigned short)f2bf(h);
            const int base = lane & ~3;
            const int a0 = __shfl(hv, base + 0);
            const int a1 = __shfl(hv, base + 1);
            const int a2 = __shfl(hv, base + 2);
            const int a3 = __shfl(hv, base + 3);
            if ((uu & 3) == 0) {
                const ull pk = (ull)(unsigned)(unsigned short)a0
                             | ((ull)(unsigned)(unsigned short)a1 << 16)
                             | ((ull)(unsigned)(unsigned short)a2 << 32)
                             | ((ull)(unsigned)(unsigned short)a3 << 48);
                __hip_atomic_store(hd, pk, __ATOMIC_RELAXED, __HIP_MEMORY_SCOPE_AGENT);
            }
        }
        // Drain h stores (s_waitcnt vmcnt(0) before s_barrier), THEN arrive.
        __syncthreads();

        if (t + 1 < T_) {
            const unsigned tgt = (unsigned)(t + 1);
            if (tid == 0)
                __hip_atomic_store(flagp, tgt, __ATOMIC_RELAXED,
                                   __HIP_MEMORY_SCOPE_AGENT);

            // out store — off the critical path, drains under the barrier wait
            *op = h;

            // x-phase for t+1 — overlapped with the barrier wait
            #pragma unroll
            for (int s = 0; s < 4; ++s) acc[s] = floatx4{0.f, 0.f, 0.f, 0.f};
            {
                const short* ax = sp + (B_ * HX_) + 1024 + kq * 128;
                bf16x8 xa[4];
                #pragma unroll
                for (int f = 0; f < 4; ++f) xa[f] = *(const bf16x8*)(ax + f * 32);
                #pragma unroll
                for (int f = 0; f < 4; ++f) {
                    #pragma unroll
                    for (int s = 0; s < 4; ++s)
                        acc[s] = __builtin_amdgcn_mfma_f32_16x16x32_bf16(xa[f], bfx[s][f], acc[s], 0, 0, 0);
                }
            }

            // FLAT one-hop barrier: wave0, one flag per lane (group = 64 flags)
            if (tid < 64) {
                for (unsigned it = 0; it < 4096u; ++it) {
                    const unsigned v0 = __hip_atomic_load(pollp, __ATOMIC_RELAXED, __HIP_MEMORY_SCOPE_AGENT);
                    if (__all(v0 >= tgt)) break;
                    __builtin_amdgcn_s_sleep(1);
                }
            }
            __syncthreads();
        } else {
            *op = h;     // last step: emit out
        }

        sp += B_ * HX_;
        hd += (B_ * HX_) / 4;     // ull increments
        op += B_ * H_;
    }
}

// ================= fallback path (proven multi-launch kernels) =================

__global__ __launch_bounds__(256) void init_all(
    const float* __restrict__ x0, short* __restrict__ hx0, float* __restrict__ cws)
{
    int idx = blockIdx.x * 256 + threadIdx.x;
    if (idx < B_ * HX_) {
        int b = idx / HX_, p = idx % HX_;
        hx0[idx] = (p < H_) ? (short)0 : f2bf(x0[b * I_ + (p - H_)]);
    } else if (idx < B_ * HX_ + 512 * 128) {
        cws[idx - B_ * HX_] = 0.0f;
    }
}

__global__ __launch_bounds__(512, 4) void lstm_step(
    const short* __restrict__ Wp, const float* __restrict__ bp,
    const short* __restrict__ hxsrc, short* __restrict__ hxdst,
    const float* __restrict__ xnext, float* __restrict__ cws,
    float* __restrict__ out_t)
{
    __shared__ __align__(16) float red[4 * 32 * RP];

    const int tid  = threadIdx.x;
    const int nt   = blockIdx.x;
    const int mh   = blockIdx.y;
    const int lane = tid & 63;
    const int wv   = tid >> 6;
    const int w    = wv & 1;
    const int kq   = wv >> 1;
    const int n16  = lane & 15;
    const int quad = lane >> 4;
    const int n0   = nt * 16;
    const int j0   = nt * 4;
    const int mrow = mh * 32 + w * 16 + n16;

    const short* __restrict__ arow = hxsrc + mrow * HX_ + kq * 384 + quad * 8;
    const short* __restrict__ brow = Wp + (size_t)(n0 + n16) * HX_ + kq * 384 + quad * 8;

    bf16x8 bfr[12];
    #pragma unroll
    for (int i = 0; i < 12; ++i) bfr[i] = *(const bf16x8*)(brow + i * 32);
    bf16x8 afr[4];
    #pragma unroll
    for (int i = 0; i < 4; ++i) afr[i] = *(const bf16x8*)(arow + i * 32);

    floatx4 acc = {0.f, 0.f, 0.f, 0.f};
    #pragma unroll
    for (int kf = 0; kf < 12; ++kf) {
        acc = __builtin_amdgcn_mfma_f32_16x16x32_bf16(afr[kf & 3], bfr[kf], acc, 0, 0, 0);
        if (kf + 4 < 12) afr[kf & 3] = *(const bf16x8*)(arow + (kf + 4) * 32);
    }

    #pragma unroll
    for (int i2 = 0; i2 < 4; ++i2)
        red[(kq * 32 + w * 16 + quad * 4 + i2) * RP + n16] = acc[i2];
    __syncthreads();

    if (tid < 128) {
        const int b_loc = tid >> 2, u = tid & 3;
        float4 bias = *(const float4*)(bp + n0 + u * 4);
        float gv[4];
        #pragma unroll
        for (int gg = 0; gg < 4; ++gg) {
            const int col = u * 4 + gg;
            float s = red[(0 * 32 + b_loc) * RP + col]
                    + red[(1 * 32 + b_loc) * RP + col]
                    + red[(2 * 32 + b_loc) * RP + col]
                    + red[(3 * 32 + b_loc) * RP + col];
            gv[gg] = s;
        }
        float F  = sigmoidf_(gv[0] + bias.x);
        float In = sigmoidf_(gv[1] + bias.y);
        float G  = tanhf_(gv[2] + bias.z);
        float O  = sigmoidf_(gv[3] + bias.w);
        const int cidx = (mh * 256 + nt) * 128 + tid;
        float c = cws[cidx];
        c = F * c + In * G;
        cws[cidx] = c;
        float h = O * tanhf_(c);
        const int gb = mh * 32 + b_loc;
        out_t[(size_t)gb * H_ + j0 + u] = h;
        hxdst[gb * HX_ + j0 + u] = f2bf(h);
    } else if (tid < 192) {
        if (xnext) {
            const int e = (mh * 256 + nt) * 64 + (tid - 128);
            const int b = e >> 9, p = e & 511;
            hxdst[b * HX_ + H_ + p] = f2bf(xnext[e]);
        }
    }
}

// ================================ launcher ================================

extern "C" void kernel_launch(void* const* d_in, const int* in_sizes, int n_in,
                              void* d_out, int out_size, void* d_ws, size_t ws_size,
                              hipStream_t stream) {
    const float* x  = (const float*)d_in[0];
    const float* Wf = (const float*)d_in[1];
    const float* bf = (const float*)d_in[2];
    const float* Wi = (const float*)d_in[3];
    const float* bi = (const float*)d_in[4];
    const float* Wc = (const float*)d_in[5];
    const float* bc = (const float*)d_in[6];
    const float* Wo = (const float*)d_in[7];
    const float* bo = (const float*)d_in[8];
    float* out = (float*)d_out;

    // ws layout (bytes):
    //   Wp    : 4096*1536*2      = 12,582,912
    //   bp    : 4096*4           =     16,384
    //   bar   : 1024*4           =      4,096
    //   hx0/1 : 2*64*1536*2      =    393,216   (fallback)
    //   cws   : 512*128*4        =    262,144   (fallback)
    //   hxall : 513*64*1536*2    = 100,859,904  (persistent)  -> total ~114.1 MB
    char* wsb = (char*)d_ws;
    size_t off = 0;
    short*    Wp    = (short*)(wsb + off);    off += (size_t)NG * HX_ * 2;
    float*    bp    = (float*)(wsb + off);    off += (size_t)NG * 4;
    unsigned* bar   = (unsigned*)(wsb + off); off += (size_t)BAR_INTS * 4;
    short*    hx0   = (short*)(wsb + off);    off += (size_t)B_ * HX_ * 2;
    short*    hx1   = (short*)(wsb + off);    off += (size_t)B_ * HX_ * 2;
    float*    cws   = (float*)(wsb + off);    off += (size_t)512 * 128 * 4;
    short*    hxall = (short*)(wsb + off);
    const size_t need = off + (size_t)(T_ + 1) * B_ * HX_ * 2;

    pack_w<<<NG, 256, 0, stream>>>(Wf, Wi, Wc, Wo, bf, bi, bc, bo, Wp, bp);

    if (ws_size >= need) {
        const int nx4 = T_ * B_ * I_ / 4;
        init_hxall<<<(nx4 + B_ * H_ / 4 + 255) / 256, 256, 0, stream>>>(x, hxall, bar);
        lstm_all<<<dim3(NBLK), dim3(512), 0, stream>>>(Wp, bp, hxall, bar, out);
        return;
    }

    init_all<<<(B_ * HX_ + 512 * 128 + 255) / 256, 256, 0, stream>>>(x, hx0, cws);
    for (int t = 0; t < T_; ++t) {
        const short* hxsrc = (t & 1) ? hx1 : hx0;
        short*       hxdst = (t & 1) ? hx0 : hx1;
        const float* xnext = (t + 1 < T_) ? (x + (size_t)(t + 1) * B_ * I_) : nullptr;
        lstm_step<<<dim3(256, 2), 512, 0, stream>>>(
            Wp, bp, hxsrc, hxdst, xnext, cws,
            out + (size_t)t * B_ * H_);
    }
}

// Round 11
// 2143.353 us; speedup vs baseline: 1.1192x; 1.1192x over previous
//
#include <hip/hip_runtime.h>
#include <hip/hip_bf16.h>
#include <math.h>

// Problem dims (fixed by the reference)
#define T_  512
#define B_  64
#define I_  512
#define H_  1024
#define HX_ 1536
#define NG  4096          // 4*H packed gate rows
#define RP  17            // fallback reduce-buffer pitch (fp32)
#define RP2 33            // reduce-buffer pitch: [kq][32 rows][32 cols]
#define NBLK 256          // persistent grid: 1 block/CU -> co-resident by construction

// Barrier: flag[mh*128 + nt] is ONE dword. Group = 128 flags = 512B = 4 lines.
#define BAR_INTS  1024    // 4KB buffer (only 256 used)

typedef __attribute__((ext_vector_type(8))) short bf16x8;
typedef __attribute__((ext_vector_type(4))) float floatx4;
typedef unsigned long long ull;

__device__ __forceinline__ float sigmoidf_(float v) { return 1.0f / (1.0f + __expf(-v)); }
__device__ __forceinline__ float tanhf_(float v) {
    float e = __expf(-2.0f * fabsf(v));
    float t = (1.0f - e) / (1.0f + e);
    return copysignf(t, v);
}
__device__ __forceinline__ short f2bf(float f) {
    union { __hip_bfloat16 b; short s; } u;
    u.b = __float2bfloat16(f);   // RNE
    return u.s;
}
__device__ __forceinline__ ull pack4bf(float a, float b, float c, float d) {
    return (ull)(unsigned short)f2bf(a)
         | ((ull)(unsigned short)f2bf(b) << 16)
         | ((ull)(unsigned short)f2bf(c) << 32)
         | ((ull)(unsigned short)f2bf(d) << 48);
}

// ---- prologue: pack Wg -> Wp [4096][HX] bf16, rows r = u*4+g; biases too ----
__global__ __launch_bounds__(256) void pack_w(
    const float* __restrict__ Wf, const float* __restrict__ Wi,
    const float* __restrict__ Wc, const float* __restrict__ Wo,
    const float* __restrict__ bf, const float* __restrict__ bi,
    const float* __restrict__ bc, const float* __restrict__ bo,
    short* __restrict__ Wp, float* __restrict__ bp)
{
    const int r = blockIdx.x;          // 0..4095
    const int u = r >> 2, g = r & 3;
    const float* src; const float* bsrc;
    switch (g) {
        case 0:  src = Wf; bsrc = bf; break;
        case 1:  src = Wi; bsrc = bi; break;
        case 2:  src = Wc; bsrc = bc; break;
        default: src = Wo; bsrc = bo; break;
    }
    src += (size_t)u * HX_;
    for (int off = threadIdx.x; off < HX_; off += 256)
        Wp[(size_t)r * HX_ + off] = f2bf(src[off]);
    if (threadIdx.x == 0) bp[r] = bsrc[u];
}

// ---- persistent-path init: stage bf16(x_t) into hxall[t] x-part for ALL t,
//      zero hxall[0] h-part, zero barrier flags ----
__global__ __launch_bounds__(256) void init_hxall(
    const float* __restrict__ x, short* __restrict__ hxall, unsigned* __restrict__ bar)
{
    const int idx = blockIdx.x * 256 + threadIdx.x;
    const int nx4 = T_ * B_ * I_ / 4;               // 4,194,304 quads
    if (idx < nx4) {
        const int e = idx * 4;                      // element index into x
        const int t = e >> 15;                      // / (B_*I_)
        const int r = e & (B_ * I_ - 1);
        const int b = r >> 9, p = r & 511;
        const float4 xv = *(const float4*)(x + (size_t)e);
        *(ull*)(hxall + (size_t)t * (B_ * HX_) + (size_t)b * HX_ + H_ + p)
            = pack4bf(xv.x, xv.y, xv.z, xv.w);
    } else if (idx < nx4 + B_ * H_ / 4) {           // zero slot-0 h-part
        const int k = (idx - nx4) * 4;
        const int b = k >> 10, p = k & 1023;
        *(ull*)(hxall + (size_t)b * HX_ + p) = 0ull;
    }
    if (idx < BAR_INTS) bar[idx] = 0u;
}

// ---- persistent LSTM v11: v9 (2174 us, verified) + per-wave producer polling ----
// 256 blocks x 512 thr, 1 block/CU. Weights pinned in regs; c in regs;
// h published via agent-scope 8B stores into T-expanded hxall (fresh lines
// each step). v11 change: wave kq consumes h cols [kq*256,kq*256+256),
// produced by exactly 32 blocks (nt' in [kq*32,kq*32+32)) -> each wave polls
// ONLY those 32 flags and proceeds independently into its h-loads (no
// post-poll __syncthreads; waves re-converge at the pre-reduce sync, and the
// LDS red buffer is dead after the drain sync every wave passed before
// polling). Wait = max over 32 producers, h-load RT overlaps residual waits.
__global__ __launch_bounds__(512, 2) void lstm_all(
    const short* __restrict__ Wp, const float* __restrict__ bp,
    short* __restrict__ hxall,            // [T_+1][B_][HX_] bf16
    unsigned* __restrict__ bar,
    float* __restrict__ out)              // [T_][B_][H_]
{
    __shared__ __align__(16) float red[4 * 32 * RP2];

    const int tid  = threadIdx.x;
    const int bid  = blockIdx.x;          // 0..255
    const int nt   = bid & 127;           // 32-gate-col group
    const int mh   = bid >> 7;            // batch half
    const int lane = tid & 63;
    const int wv   = tid >> 6;            // 0..7
    const int w    = wv & 1;              // M 16-row half
    const int kq   = wv >> 1;             // K quarter
    const int n16  = lane & 15;
    const int quad = lane >> 4;
    const int n0   = nt * 32;             // packed gate-col base (32 cols)
    const int j0   = nt * 8;              // hidden-unit base (8 units)
    const int mrow = mh * 32 + w * 16 + n16;

    // Weights: pinned for all 512 steps. Two N-tiles: 2x(8 h + 4 x) frags.
    bf16x8 bfh0[8], bfh1[8], bfx0[4], bfx1[4];
    {
        const short* br0 = Wp + (size_t)(n0 + n16) * HX_ + quad * 8;
        const short* br1 = Wp + (size_t)(n0 + 16 + n16) * HX_ + quad * 8;
        #pragma unroll
        for (int f = 0; f < 8; ++f) {
            bfh0[f] = *(const bf16x8*)(br0 + kq * 256 + f * 32);
            bfh1[f] = *(const bf16x8*)(br1 + kq * 256 + f * 32);
        }
        #pragma unroll
        for (int f = 0; f < 4; ++f) {
            bfx0[f] = *(const bf16x8*)(br0 + 1024 + kq * 128 + f * 32);
            bfx1[f] = *(const bf16x8*)(br1 + 1024 + kq * 128 + f * 32);
        }
    }

    // Epilogue-role constants (tid < 256): thread = (row b_loc, unit j0+uu)
    const int b_loc = tid >> 3;           // 0..31
    const int uu    = tid & 7;            // 0..7
    const int gb    = mh * 32 + b_loc;
    const float4 bias = *(const float4*)(bp + n0 + uu * 4);
    float c = 0.0f;

    // Running pointers (advance one time-slot per step)
    const short* sp = hxall + (size_t)mrow * HX_ + quad * 8;                 // A row base, slot t
    ull* hd = (ull*)(hxall + (size_t)(B_ * HX_) + (size_t)gb * HX_ + j0 + (uu & 4)); // h dst slot t+1
    float* op = out + (size_t)gb * H_ + j0 + uu;

    unsigned* const flagp = bar + (unsigned)(mh * 128 + nt);                 // own dword
    // v11: this wave's 32 producer flags (h cols kq*256.. come from blocks
    // nt' = kq*32 .. kq*32+31). Lanes 32-63 duplicate lanes 0-31 (harmless).
    const unsigned* const prodp = bar + (unsigned)(mh * 128 + kq * 32 + (lane & 31));

    // x-phase for t=0 (x-part of A is init-staged for all t)
    floatx4 acc0 = {0.f, 0.f, 0.f, 0.f}, acc1 = {0.f, 0.f, 0.f, 0.f};
    {
        const short* ax = sp + 1024 + kq * 128;
        bf16x8 xa[4];
        #pragma unroll
        for (int f = 0; f < 4; ++f) xa[f] = *(const bf16x8*)(ax + f * 32);
        #pragma unroll
        for (int f = 0; f < 4; ++f) {
            acc0 = __builtin_amdgcn_mfma_f32_16x16x32_bf16(xa[f], bfx0[f], acc0, 0, 0, 0);
            acc1 = __builtin_amdgcn_mfma_f32_16x16x32_bf16(xa[f], bfx1[f], acc1, 0, 0, 0);
        }
    }

    for (int t = 0; t < T_; ++t) {
        // h-phase: 8 shared A-frag loads feed BOTH N-tiles (16 MFMAs)
        {
            const short* ah = sp + kq * 256;
            bf16x8 ha[8];
            #pragma unroll
            for (int i = 0; i < 8; ++i) ha[i] = *(const bf16x8*)(ah + i * 32);
            #pragma unroll
            for (int kf = 0; kf < 8; ++kf) {
                acc0 = __builtin_amdgcn_mfma_f32_16x16x32_bf16(ha[kf], bfh0[kf], acc0, 0, 0, 0);
                acc1 = __builtin_amdgcn_mfma_f32_16x16x32_bf16(ha[kf], bfh1[kf], acc1, 0, 0, 0);
            }
        }

        // C/D layout: batch row = quad*4 + reg (within w-half), gate col = n16
        #pragma unroll
        for (int i2 = 0; i2 < 4; ++i2) {
            const int rr = (kq * 32 + w * 16 + quad * 4 + i2) * RP2;
            red[rr + n16]      = acc0[i2];
            red[rr + 16 + n16] = acc1[i2];
        }
        __syncthreads();   // sync #1: all partials in LDS

        float h = 0.0f;
        if (tid < 256) {
            float gv[4];
            #pragma unroll
            for (int gg = 0; gg < 4; ++gg) {
                const int col = uu * 4 + gg;
                gv[gg] = red[(0 * 32 + b_loc) * RP2 + col]
                       + red[(1 * 32 + b_loc) * RP2 + col]
                       + red[(2 * 32 + b_loc) * RP2 + col]
                       + red[(3 * 32 + b_loc) * RP2 + col];
            }
            const float F  = sigmoidf_(gv[0] + bias.x);
            const float In = sigmoidf_(gv[1] + bias.y);
            const float G  = tanhf_(gv[2] + bias.z);
            const float O  = sigmoidf_(gv[3] + bias.w);
            c = F * c + In * G;
            h = O * tanhf_(c);
            // pack 4 adjacent units (same b_loc) into one 8B agent store
            const int hv = (int)(unsigned short)f2bf(h);
            const int base = lane & ~3;
            const int a0 = __shfl(hv, base + 0);
            const int a1 = __shfl(hv, base + 1);
            const int a2 = __shfl(hv, base + 2);
            const int a3 = __shfl(hv, base + 3);
            if ((uu & 3) == 0) {
                const ull pk = (ull)(unsigned)(unsigned short)a0
                             | ((ull)(unsigned)(unsigned short)a1 << 16)
                             | ((ull)(unsigned)(unsigned short)a2 << 32)
                             | ((ull)(unsigned)(unsigned short)a3 << 48);
                __hip_atomic_store(hd, pk, __ATOMIC_RELAXED, __HIP_MEMORY_SCOPE_AGENT);
            }
        }
        // sync #2: drain h stores (s_waitcnt vmcnt(0) before s_barrier),
        // THEN arrive — h durable at the coherence point before the flag.
        // Also: after this sync, red is dead -> next step may rewrite it
        // without further synchronization.
        __syncthreads();

        if (t + 1 < T_) {
            const unsigned tgt = (unsigned)(t + 1);
            if (tid == 0)
                __hip_atomic_store(flagp, tgt, __ATOMIC_RELAXED,
                                   __HIP_MEMORY_SCOPE_AGENT);

            // out store — off the critical path, drains under the wait
            if (tid < 256) *op = h;

            // x-phase for t+1 — overlapped with the wait
            acc0 = floatx4{0.f, 0.f, 0.f, 0.f};
            acc1 = floatx4{0.f, 0.f, 0.f, 0.f};
            {
                const short* ax = sp + (B_ * HX_) + 1024 + kq * 128;
                bf16x8 xa[4];
                #pragma unroll
                for (int f = 0; f < 4; ++f) xa[f] = *(const bf16x8*)(ax + f * 32);
                #pragma unroll
                for (int f = 0; f < 4; ++f) {
                    acc0 = __builtin_amdgcn_mfma_f32_16x16x32_bf16(xa[f], bfx0[f], acc0, 0, 0, 0);
                    acc1 = __builtin_amdgcn_mfma_f32_16x16x32_bf16(xa[f], bfx1[f], acc1, 0, 0, 0);
                }
            }

            // v11: per-wave poll on this wave's 32 producer flags; each wave
            // proceeds independently into its h-loads (no block-wide sync).
            for (unsigned it = 0; it < 4096u; ++it) {
                const unsigned v0 = __hip_atomic_load(prodp, __ATOMIC_RELAXED,
                                                      __HIP_MEMORY_SCOPE_AGENT);
                if (__all(v0 >= tgt)) break;
                __builtin_amdgcn_s_sleep(1);
            }
        } else {
            if (tid < 256) *op = h;     // last step: emit out
        }

        sp += B_ * HX_;
        hd += (B_ * HX_) / 4;     // ull increments
        op += B_ * H_;
    }
}

// ================= fallback path (proven multi-launch kernels) =================

__global__ __launch_bounds__(256) void init_all(
    const float* __restrict__ x0, short* __restrict__ hx0, float* __restrict__ cws)
{
    int idx = blockIdx.x * 256 + threadIdx.x;
    if (idx < B_ * HX_) {
        int b = idx / HX_, p = idx % HX_;
        hx0[idx] = (p < H_) ? (short)0 : f2bf(x0[b * I_ + (p - H_)]);
    } else if (idx < B_ * HX_ + 512 * 128) {
        cws[idx - B_ * HX_] = 0.0f;
    }
}

__global__ __launch_bounds__(512, 4) void lstm_step(
    const short* __restrict__ Wp, const float* __restrict__ bp,
    const short* __restrict__ hxsrc, short* __restrict__ hxdst,
    const float* __restrict__ xnext, float* __restrict__ cws,
    float* __restrict__ out_t)
{
    __shared__ __align__(16) float red[4 * 32 * RP];

    const int tid  = threadIdx.x;
    const int nt   = blockIdx.x;
    const int mh   = blockIdx.y;
    const int lane = tid & 63;
    const int wv   = tid >> 6;
    const int w    = wv & 1;
    const int kq   = wv >> 1;
    const int n16  = lane & 15;
    const int quad = lane >> 4;
    const int n0   = nt * 16;
    const int j0   = nt * 4;
    const int mrow = mh * 32 + w * 16 + n16;

    const short* __restrict__ arow = hxsrc + mrow * HX_ + kq * 384 + quad * 8;
    const short* __restrict__ brow = Wp + (size_t)(n0 + n16) * HX_ + kq * 384 + quad * 8;

    bf16x8 bfr[12];
    #pragma unroll
    for (int i = 0; i < 12; ++i) bfr[i] = *(const bf16x8*)(brow + i * 32);
    bf16x8 afr[4];
    #pragma unroll
    for (int i = 0; i < 4; ++i) afr[i] = *(const bf16x8*)(arow + i * 32);

    floatx4 acc = {0.f, 0.f, 0.f, 0.f};
    #pragma unroll
    for (int kf = 0; kf < 12; ++kf) {
        acc = __builtin_amdgcn_mfma_f32_16x16x32_bf16(afr[kf & 3], bfr[kf], acc, 0, 0, 0);
        if (kf + 4 < 12) afr[kf & 3] = *(const bf16x8*)(arow + (kf + 4) * 32);
    }

    #pragma unroll
    for (int i2 = 0; i2 < 4; ++i2)
        red[(kq * 32 + w * 16 + quad * 4 + i2) * RP + n16] = acc[i2];
    __syncthreads();

    if (tid < 128) {
        const int b_loc = tid >> 2, u = tid & 3;
        float4 bias = *(const float4*)(bp + n0 + u * 4);
        float gv[4];
        #pragma unroll
        for (int gg = 0; gg < 4; ++gg) {
            const int col = u * 4 + gg;
            float s = red[(0 * 32 + b_loc) * RP + col]
                    + red[(1 * 32 + b_loc) * RP + col]
                    + red[(2 * 32 + b_loc) * RP + col]
                    + red[(3 * 32 + b_loc) * RP + col];
            gv[gg] = s;
        }
        float F  = sigmoidf_(gv[0] + bias.x);
        float In = sigmoidf_(gv[1] + bias.y);
        float G  = tanhf_(gv[2] + bias.z);
        float O  = sigmoidf_(gv[3] + bias.w);
        const int cidx = (mh * 256 + nt) * 128 + tid;
        float c = cws[cidx];
        c = F * c + In * G;
        cws[cidx] = c;
        float h = O * tanhf_(c);
        const int gb = mh * 32 + b_loc;
        out_t[(size_t)gb * H_ + j0 + u] = h;
        hxdst[gb * HX_ + j0 + u] = f2bf(h);
    } else if (tid < 192) {
        if (xnext) {
            const int e = (mh * 256 + nt) * 64 + (tid - 128);
            const int b = e >> 9, p = e & 511;
            hxdst[b * HX_ + H_ + p] = f2bf(xnext[e]);
        }
    }
}

// ================================ launcher ================================

extern "C" void kernel_launch(void* const* d_in, const int* in_sizes, int n_in,
                              void* d_out, int out_size, void* d_ws, size_t ws_size,
                              hipStream_t stream) {
    const float* x  = (const float*)d_in[0];
    const float* Wf = (const float*)d_in[1];
    const float* bf = (const float*)d_in[2];
    const float* Wi = (const float*)d_in[3];
    const float* bi = (const float*)d_in[4];
    const float* Wc = (const float*)d_in[5];
    const float* bc = (const float*)d_in[6];
    const float* Wo = (const float*)d_in[7];
    const float* bo = (const float*)d_in[8];
    float* out = (float*)d_out;

    // ws layout (bytes):
    //   Wp    : 4096*1536*2      = 12,582,912
    //   bp    : 4096*4           =     16,384
    //   bar   : 1024*4           =      4,096
    //   hx0/1 : 2*64*1536*2      =    393,216   (fallback)
    //   cws   : 512*128*4        =    262,144   (fallback)
    //   hxall : 513*64*1536*2    = 100,859,904  (persistent)  -> total ~114.1 MB
    char* wsb = (char*)d_ws;
    size_t off = 0;
    short*    Wp    = (short*)(wsb + off);    off += (size_t)NG * HX_ * 2;
    float*    bp    = (float*)(wsb + off);    off += (size_t)NG * 4;
    unsigned* bar   = (unsigned*)(wsb + off); off += (size_t)BAR_INTS * 4;
    short*    hx0   = (short*)(wsb + off);    off += (size_t)B_ * HX_ * 2;
    short*    hx1   = (short*)(wsb + off);    off += (size_t)B_ * HX_ * 2;
    float*    cws   = (float*)(wsb + off);    off += (size_t)512 * 128 * 4;
    short*    hxall = (short*)(wsb + off);
    const size_t need = off + (size_t)(T_ + 1) * B_ * HX_ * 2;

    pack_w<<<NG, 256, 0, stream>>>(Wf, Wi, Wc, Wo, bf, bi, bc, bo, Wp, bp);

    if (ws_size >= need) {
        const int nx4 = T_ * B_ * I_ / 4;
        init_hxall<<<(nx4 + B_ * H_ / 4 + 255) / 256, 256, 0, stream>>>(x, hxall, bar);
        lstm_all<<<dim3(NBLK), dim3(512), 0, stream>>>(Wp, bp, hxall, bar, out);
        return;
    }

    init_all<<<(B_ * HX_ + 512 * 128 + 255) / 256, 256, 0, stream>>>(x, hx0, cws);
    for (int t = 0; t < T_; ++t) {
        const short* hxsrc = (t & 1) ? hx1 : hx0;
        short*       hxdst = (t & 1) ? hx0 : hx1;
        const float* xnext = (t + 1 < T_) ? (x + (size_t)(t + 1) * B_ * I_) : nullptr;
        lstm_step<<<dim3(256, 2), 512, 0, stream>>>(
            Wp, bp, hxsrc, hxdst, xnext, cws,
            out + (size_t)t * B_ * H_);
    }
}